// Round 1
// baseline (1266.320 us; speedup 1.0000x reference)
//
#include <hip/hip_runtime.h>

#define NPTS 65536
#define KC   1024
#define DD   512

#define BM 64
#define BN 128
#define BK 16

// ---------------- kernel 1: c2[k] = ||center_k||^2 ----------------
__global__ __launch_bounds__(256) void c2_kernel(const float* __restrict__ centers,
                                                 float* __restrict__ c2) {
  int wave = (blockIdx.x * 256 + threadIdx.x) >> 6;
  int lane = threadIdx.x & 63;
  if (wave >= KC) return;
  const float4* c4 = (const float4*)(centers + (size_t)wave * DD);
  float s = 0.f;
#pragma unroll
  for (int j = 0; j < 2; j++) {            // 512 floats = 128 float4 = 2/lane
    float4 v = c4[lane + 64 * j];
    s += v.x * v.x + v.y * v.y + v.z * v.z + v.w * v.w;
  }
#pragma unroll
  for (int off = 32; off; off >>= 1) s += __shfl_down(s, off, 64);
  if (lane == 0) c2[wave] = s;
}

// ---------------- kernel 2: per-point argmin over centers ----------------
// argmin_k ||x-c||^2 == argmin_k (c2[k] - 2*dot(x,c_k))  (x2 is row-constant)
__global__ __launch_bounds__(256) void argmin_kernel(
    const float* __restrict__ x, const float* __restrict__ centers,
    const float* __restrict__ c2, float* __restrict__ ynew_out) {
  __shared__ float As[BK][BM + 4];   // +4 floats keeps 16B alignment, breaks conflicts
  __shared__ float Bs[BK][BN + 4];

  const int t  = threadIdx.x;
  const int ty = t >> 4;   // 0..15 : row group (4 rows each)
  const int tx = t & 15;   // 0..15 : col group (8 cols each)
  const size_t row0 = (size_t)blockIdx.x * BM;

  // staging: each thread loads one float4 of A, two float4 of B per k-step
  const int ar = t >> 2;          // 0..63
  const int ac = (t & 3) << 2;    // 0,4,8,12

  float best[4];
  int   bidx[4];
#pragma unroll
  for (int i = 0; i < 4; i++) { best[i] = 3.4e38f; bidx[i] = 0; }

  const float* xa = x + (row0 + ar) * DD + ac;

  for (int n0 = 0; n0 < KC; n0 += BN) {
    float acc[4][8];
#pragma unroll
    for (int i = 0; i < 4; i++)
#pragma unroll
      for (int j = 0; j < 8; j++) acc[i][j] = 0.f;

    const float* ba = centers + (size_t)(n0 + ar) * DD + ac;

    for (int k0 = 0; k0 < DD; k0 += BK) {
      float4 av  = *(const float4*)(xa + k0);
      float4 bv0 = *(const float4*)(ba + k0);
      float4 bv1 = *(const float4*)(ba + (size_t)64 * DD + k0);
      __syncthreads();   // previous iteration's reads complete before overwrite
      As[ac + 0][ar] = av.x;  As[ac + 1][ar] = av.y;
      As[ac + 2][ar] = av.z;  As[ac + 3][ar] = av.w;
      Bs[ac + 0][ar] = bv0.x; Bs[ac + 1][ar] = bv0.y;
      Bs[ac + 2][ar] = bv0.z; Bs[ac + 3][ar] = bv0.w;
      Bs[ac + 0][ar + 64] = bv1.x; Bs[ac + 1][ar + 64] = bv1.y;
      Bs[ac + 2][ar + 64] = bv1.z; Bs[ac + 3][ar + 64] = bv1.w;
      __syncthreads();
#pragma unroll
      for (int kk = 0; kk < BK; kk++) {
        float4 a  = *(const float4*)&As[kk][ty << 2];
        float4 b0 = *(const float4*)&Bs[kk][tx << 3];
        float4 b1 = *(const float4*)&Bs[kk][(tx << 3) + 4];
        float ai[4] = {a.x, a.y, a.z, a.w};
        float bj[8] = {b0.x, b0.y, b0.z, b0.w, b1.x, b1.y, b1.z, b1.w};
#pragma unroll
        for (int i = 0; i < 4; i++)
#pragma unroll
          for (int j = 0; j < 8; j++) acc[i][j] = fmaf(ai[i], bj[j], acc[i][j]);
      }
    }

    // fold this center tile into the running argmin
#pragma unroll
    for (int j = 0; j < 8; j++) {
      int col = n0 + (tx << 3) + j;
      float v0 = c2[col];
#pragma unroll
      for (int i = 0; i < 4; i++) {
        float v = fmaf(-2.f, acc[i][j], v0);
        if (v < best[i]) { best[i] = v; bidx[i] = col; }  // strict <: keeps lowest idx
      }
    }
  }

  // reduce across the 16 tx lanes sharing each point row (lane bits 0..3 = tx)
#pragma unroll
  for (int i = 0; i < 4; i++) {
    float v = best[i];
    int idx = bidx[i];
#pragma unroll
    for (int off = 8; off; off >>= 1) {
      float ov = __shfl_xor(v, off, 64);
      int   oi = __shfl_xor(idx, off, 64);
      if (ov < v || (ov == v && oi < idx)) { v = ov; idx = oi; }
    }
    if (tx == 0) ynew_out[row0 + (ty << 2) + i] = (float)idx;
  }
}

// ---------------- kernel 3: loss = sum_i ||x_i - c_{y[i]}||^2 ----------------
__global__ __launch_bounds__(256) void loss_kernel(
    const float* __restrict__ x, const int* __restrict__ y,
    const float* __restrict__ centers, float* __restrict__ loss) {
  __shared__ float partial[4];
  const int wave = threadIdx.x >> 6;
  const int lane = threadIdx.x & 63;
  const int i = blockIdx.x * 4 + wave;
  const float4* x4 = (const float4*)(x + (size_t)i * DD);
  const float4* c4 = (const float4*)(centers + (size_t)y[i] * DD);
  float s = 0.f;
#pragma unroll
  for (int j = 0; j < 2; j++) {
    float4 xv = x4[lane + 64 * j];
    float4 cv = c4[lane + 64 * j];
    float dx = xv.x - cv.x, dy = xv.y - cv.y, dz = xv.z - cv.z, dw = xv.w - cv.w;
    s += dx * dx + dy * dy + dz * dz + dw * dw;
  }
#pragma unroll
  for (int off = 32; off; off >>= 1) s += __shfl_down(s, off, 64);
  if (lane == 0) partial[wave] = s;
  __syncthreads();
  if (threadIdx.x == 0)
    atomicAdd(loss, partial[0] + partial[1] + partial[2] + partial[3]);
}

extern "C" void kernel_launch(void* const* d_in, const int* in_sizes, int n_in,
                              void* d_out, int out_size, void* d_ws, size_t ws_size,
                              hipStream_t stream) {
  const float* x       = (const float*)d_in[0];
  const int*   y       = (const int*)d_in[1];
  const float* centers = (const float*)d_in[2];
  float* out = (float*)d_out;     // out[0] = loss, out[1..65536] = ynew (as float)
  float* c2  = (float*)d_ws;      // K floats of scratch

  hipMemsetAsync(d_out, 0, sizeof(float), stream);  // zero the loss accumulator
  c2_kernel<<<KC / 4, 256, 0, stream>>>(centers, c2);
  argmin_kernel<<<NPTS / BM, 256, 0, stream>>>(x, centers, c2, out + 1);
  loss_kernel<<<NPTS / 4, 256, 0, stream>>>(x, y, centers, out);
}

// Round 2
// 423.713 us; speedup vs baseline: 2.9886x; 2.9886x over previous
//
#include <hip/hip_runtime.h>

#define NPTS 65536
#define KC   1024
#define DD   512

using bf16x8 = __attribute__((ext_vector_type(8))) __bf16;
using f32x4  = __attribute__((ext_vector_type(4))) float;

// LDS fragment slot for (row-in-tile, k-oct). Reads (lane l -> row=l&15, oct=l>>4)
// are consecutive-16B => conflict-free. The ^4 swizzle on octs 2,3 makes the
// staging writes (rows 4q..4q+3 x octs {0,2} per 8-lane cycle) conflict-free too.
#define SLOT(row, oct) (16 * (oct) + (((row) & 15) ^ (((oct) & 2) << 1)))

// split one fp32 into hi/lo bf16 (truncation): f = hi + lo + O(2^-16 f)
__device__ __forceinline__ void split_pack(const float4& a, const float4& b,
                                           uint4& hi, uint4& lo) {
  float f[8] = {a.x, a.y, a.z, a.w, b.x, b.y, b.z, b.w};
  uint hw[4], lw[4];
#pragma unroll
  for (int i = 0; i < 4; i++) {
    uint e0 = __float_as_uint(f[2 * i]), e1 = __float_as_uint(f[2 * i + 1]);
    hw[i] = (e0 >> 16) | (e1 & 0xffff0000u);
    float l0 = f[2 * i]     - __uint_as_float(e0 & 0xffff0000u);
    float l1 = f[2 * i + 1] - __uint_as_float(e1 & 0xffff0000u);
    lw[i] = (__float_as_uint(l0) >> 16) | (__float_as_uint(l1) & 0xffff0000u);
  }
  hi = make_uint4(hw[0], hw[1], hw[2], hw[3]);
  lo = make_uint4(lw[0], lw[1], lw[2], lw[3]);
}

// ---------------- c2[k] = ||center_k||^2 ----------------
__global__ __launch_bounds__(256) void c2_kernel(const float* __restrict__ centers,
                                                 float* __restrict__ c2) {
  int wave = (blockIdx.x * 256 + threadIdx.x) >> 6;
  int lane = threadIdx.x & 63;
  const float4* c4 = (const float4*)(centers + (size_t)wave * DD);
  float s = 0.f;
#pragma unroll
  for (int j = 0; j < 2; j++) {
    float4 v = c4[lane + 64 * j];
    s += v.x * v.x + v.y * v.y + v.z * v.z + v.w * v.w;
  }
#pragma unroll
  for (int off = 32; off; off >>= 1) s += __shfl_down(s, off, 64);
  if (lane == 0) c2[wave] = s;
}

// ---------------- MFMA argmin: dist = c2[n] - 2*dot(x_m, c_n) ----------------
__global__ __launch_bounds__(256, 2) void argmin_kernel(
    const float* __restrict__ x, const float* __restrict__ centers,
    const float* __restrict__ c2, float* __restrict__ ynew_out) {
  __shared__ uint4 Ah[512], Al[512], Bh[512], Bl[512];  // 4 x 8KB

  const int t = threadIdx.x;
  const int w = t >> 6, l = t & 63;
  const int wm = w >> 1, wn = w & 1;  // wave covers rows wm*64.., cols wn*64..
  const size_t row0 = (size_t)blockIdx.x * 128;

  // staging: thread t -> row srow (0..127), k-half h; 16 fp32 of A + 16 of B
  const int srow = t >> 1, h = t & 1;
  const int mt = srow >> 4;
  const int so0 = mt * 64 + SLOT(srow, 2 * h);
  const int so1 = mt * 64 + SLOT(srow, 2 * h + 1);

  // reader fragment slots (same for A and B regions, different tile index)
  const int rs = SLOT(l & 15, l >> 4);

  const float* xp = x + (row0 + srow) * DD + h * 16;

  float best[16];
  int bidx[16];
#pragma unroll
  for (int i = 0; i < 16; i++) { best[i] = 3.4e38f; bidx[i] = 0; }

  for (int n0 = 0; n0 < KC; n0 += 128) {
    const float* bp = centers + (size_t)(n0 + srow) * DD + h * 16;

    f32x4 acc[4][4];
#pragma unroll
    for (int i = 0; i < 4; i++)
#pragma unroll
      for (int j = 0; j < 4; j++) acc[i][j] = (f32x4){0.f, 0.f, 0.f, 0.f};

    float4 ra[4], rb[4];
#pragma unroll
    for (int q = 0; q < 4; q++) {
      ra[q] = *(const float4*)(xp + q * 4);
      rb[q] = *(const float4*)(bp + q * 4);
    }

    for (int ks = 0; ks < 16; ks++) {
      uint4 ah0, al0, ah1, al1, bh0, bl0, bh1, bl1;
      split_pack(ra[0], ra[1], ah0, al0);
      split_pack(ra[2], ra[3], ah1, al1);
      split_pack(rb[0], rb[1], bh0, bl0);
      split_pack(rb[2], rb[3], bh1, bl1);
      __syncthreads();  // prev iteration's fragment reads done
      Ah[so0] = ah0; Al[so0] = al0;
      Ah[so1] = ah1; Al[so1] = al1;
      Bh[so0] = bh0; Bl[so0] = bl0;
      Bh[so1] = bh1; Bl[so1] = bl1;
      __syncthreads();
      if (ks < 15) {  // prefetch next k-chunk while MFMAs run
#pragma unroll
        for (int q = 0; q < 4; q++) {
          ra[q] = *(const float4*)(xp + (ks + 1) * 32 + q * 4);
          rb[q] = *(const float4*)(bp + (ks + 1) * 32 + q * 4);
        }
      }
      bf16x8 afh[4], afl[4], bfh[4], bfl[4];
#pragma unroll
      for (int i = 0; i < 4; i++) {
        afh[i] = *(const bf16x8*)&Ah[(wm * 4 + i) * 64 + rs];
        afl[i] = *(const bf16x8*)&Al[(wm * 4 + i) * 64 + rs];
        bfh[i] = *(const bf16x8*)&Bh[(wn * 4 + i) * 64 + rs];
        bfl[i] = *(const bf16x8*)&Bl[(wn * 4 + i) * 64 + rs];
      }
#pragma unroll
      for (int i = 0; i < 4; i++)
#pragma unroll
        for (int j = 0; j < 4; j++) {
          acc[i][j] = __builtin_amdgcn_mfma_f32_16x16x32_bf16(afh[i], bfh[j], acc[i][j], 0, 0, 0);
          acc[i][j] = __builtin_amdgcn_mfma_f32_16x16x32_bf16(afl[i], bfh[j], acc[i][j], 0, 0, 0);
          acc[i][j] = __builtin_amdgcn_mfma_f32_16x16x32_bf16(afh[i], bfl[j], acc[i][j], 0, 0, 0);
        }
    }

    // fold this 128-center tile into the running argmin.
    // C/D layout: col(n)=lane&15, row(m)=(lane>>4)*4+reg  [m89-verified]
#pragma unroll
    for (int j = 0; j < 4; j++) {
      int n = n0 + wn * 64 + j * 16 + (l & 15);
      float cc = c2[n];
#pragma unroll
      for (int i = 0; i < 4; i++)
#pragma unroll
        for (int r = 0; r < 4; r++) {
          float v = fmaf(-2.f, acc[i][j][r], cc);
          int bi = i * 4 + r;
          if (v < best[bi]) { best[bi] = v; bidx[bi] = n; }
        }
    }
  }

  // reduce across the 16 lanes (same quad) that share each output row
#pragma unroll
  for (int bi = 0; bi < 16; bi++) {
    float v = best[bi];
    int idx = bidx[bi];
#pragma unroll
    for (int off = 8; off; off >>= 1) {
      float ov = __shfl_xor(v, off, 64);
      int oi = __shfl_xor(idx, off, 64);
      if (ov < v || (ov == v && oi < idx)) { v = ov; idx = oi; }
    }
    if ((l & 15) == 0) {
      int m = wm * 64 + (bi >> 2) * 16 + (l >> 4) * 4 + (bi & 3);
      ynew_out[row0 + m] = (float)idx;
    }
  }
}

// ---------------- loss: two-stage, atomic-free ----------------
__global__ __launch_bounds__(256) void loss_partial(
    const float* __restrict__ x, const int* __restrict__ y,
    const float* __restrict__ centers, float* __restrict__ partial) {
  const int w = threadIdx.x >> 6, l = threadIdx.x & 63;
  const int base = blockIdx.x * 64 + w * 16;
  float s = 0.f;
  for (int p = 0; p < 16; p++) {
    int i = base + p;
    const float4* x4 = (const float4*)(x + (size_t)i * DD);
    const float4* c4 = (const float4*)(centers + (size_t)y[i] * DD);
#pragma unroll
    for (int j = 0; j < 2; j++) {
      float4 xv = x4[l + 64 * j], cv = c4[l + 64 * j];
      float dx = xv.x - cv.x, dy = xv.y - cv.y, dz = xv.z - cv.z, dw = xv.w - cv.w;
      s += dx * dx + dy * dy + dz * dz + dw * dw;
    }
  }
#pragma unroll
  for (int off = 32; off; off >>= 1) s += __shfl_down(s, off, 64);
  __shared__ float ps[4];
  if (l == 0) ps[w] = s;
  __syncthreads();
  if (threadIdx.x == 0) partial[blockIdx.x] = ps[0] + ps[1] + ps[2] + ps[3];
}

__global__ __launch_bounds__(256) void loss_final(const float* __restrict__ partial,
                                                  float* __restrict__ out) {
  float s = 0.f;
#pragma unroll
  for (int j = 0; j < 4; j++) s += partial[threadIdx.x + 256 * j];
#pragma unroll
  for (int off = 32; off; off >>= 1) s += __shfl_down(s, off, 64);
  __shared__ float ps[4];
  if ((threadIdx.x & 63) == 0) ps[threadIdx.x >> 6] = s;
  __syncthreads();
  if (threadIdx.x == 0) out[0] = ps[0] + ps[1] + ps[2] + ps[3];
}

extern "C" void kernel_launch(void* const* d_in, const int* in_sizes, int n_in,
                              void* d_out, int out_size, void* d_ws, size_t ws_size,
                              hipStream_t stream) {
  const float* x       = (const float*)d_in[0];
  const int*   y       = (const int*)d_in[1];
  const float* centers = (const float*)d_in[2];
  float* out = (float*)d_out;          // out[0] = loss, out[1..] = ynew as float
  float* c2      = (float*)d_ws;       // KC floats
  float* partial = c2 + KC;            // 1024 floats

  c2_kernel<<<KC / 4, 256, 0, stream>>>(centers, c2);
  argmin_kernel<<<NPTS / 128, 256, 0, stream>>>(x, centers, c2, out + 1);
  loss_partial<<<NPTS / 64, 256, 0, stream>>>(x, y, centers, partial);
  loss_final<<<1, 256, 0, stream>>>(partial, out);
}

// Round 3
// 289.195 us; speedup vs baseline: 4.3788x; 1.4651x over previous
//
#include <hip/hip_runtime.h>

#define NPTS 65536
#define KC   1024
#define DD   512

using bf16x8 = __attribute__((ext_vector_type(8))) __bf16;
using f32x4  = __attribute__((ext_vector_type(4))) float;

// ---- async global->LDS, 16B per lane. LDS dest = wave-uniform base + lane*16.
__device__ __forceinline__ void gld_lds16(const void* g, void* lds_base) {
  __builtin_amdgcn_global_load_lds(
      (const __attribute__((address_space(1))) unsigned int*)(uintptr_t)g,
      (__attribute__((address_space(3))) unsigned int*)(unsigned int)(uintptr_t)lds_base,
      16, 0, 0);
}

// pack float4 -> 4 bf16 (truncation)
__device__ __forceinline__ uint2 pack4(const float4& v) {
  uint2 r;
  r.x = (__float_as_uint(v.x) >> 16) | (__float_as_uint(v.y) & 0xffff0000u);
  r.y = (__float_as_uint(v.z) >> 16) | (__float_as_uint(v.w) & 0xffff0000u);
  return r;
}

// ================= FAST PATH =================

// convert x -> bf16 rows in ws, and compute exact-fp32 loss partials.
// block = 256 (4 waves); block handles 64 rows, one wave per row x 16.
__global__ __launch_bounds__(256) void convert_x_loss(
    const float* __restrict__ x, const int* __restrict__ y,
    const float* __restrict__ centers, uint4* __restrict__ xb,
    float* __restrict__ partial) {
  const int w = threadIdx.x >> 6, l = threadIdx.x & 63;
  const int base = blockIdx.x * 64 + w * 16;
  const float4* xf4 = (const float4*)x;
  const float4* cf4 = (const float4*)centers;
  float s = 0.f;
  for (int p = 0; p < 16; p++) {
    const int row = base + p;
    float4 a = xf4[row * 128 + 2 * l];
    float4 b = xf4[row * 128 + 2 * l + 1];
    uint2 pa = pack4(a), pb = pack4(b);
    xb[row * 64 + l] = make_uint4(pa.x, pa.y, pb.x, pb.y);
    const int yr = y[row];
    float4 ca = cf4[yr * 128 + 2 * l];
    float4 cb = cf4[yr * 128 + 2 * l + 1];
    float d0 = a.x - ca.x, d1 = a.y - ca.y, d2 = a.z - ca.z, d3 = a.w - ca.w;
    float d4 = b.x - cb.x, d5 = b.y - cb.y, d6 = b.z - cb.z, d7 = b.w - cb.w;
    s += d0 * d0 + d1 * d1 + d2 * d2 + d3 * d3;
    s += d4 * d4 + d5 * d5 + d6 * d6 + d7 * d7;
  }
#pragma unroll
  for (int off = 32; off; off >>= 1) s += __shfl_down(s, off, 64);
  __shared__ float ps[4];
  if (l == 0) ps[w] = s;
  __syncthreads();
  if (threadIdx.x == 0) partial[blockIdx.x] = ps[0] + ps[1] + ps[2] + ps[3];
}

// centers -> bf16 + c2.  one wave per center row.
__global__ __launch_bounds__(256) void convert_c(
    const float* __restrict__ centers, uint4* __restrict__ cb,
    float* __restrict__ c2) {
  const int row = (blockIdx.x * 256 + threadIdx.x) >> 6;
  const int l = threadIdx.x & 63;
  const float4* cf4 = (const float4*)centers;
  float4 a = cf4[row * 128 + 2 * l];
  float4 b = cf4[row * 128 + 2 * l + 1];
  uint2 pa = pack4(a), pb = pack4(b);
  cb[row * 64 + l] = make_uint4(pa.x, pa.y, pb.x, pb.y);
  float s = a.x * a.x + a.y * a.y + a.z * a.z + a.w * a.w +
            b.x * b.x + b.y * b.y + b.z * b.z + b.w * b.w;
#pragma unroll
  for (int off = 32; off; off >>= 1) s += __shfl_down(s, off, 64);
  if (l == 0) c2[row] = s;
}

// single-pass bf16 MFMA argmin.  A = xb [65536 x 512 bf16], B = cb [1024 x 512].
// LDS tiles [128 rows][64 bf16] staged via global_load_lds with XOR-swizzled
// source permutation: slot(r, oct) = oct ^ (r & 7)  => conflict-free b128 frags.
__global__ __launch_bounds__(256, 2) void gemm_argmin(
    const uint4* __restrict__ xb, const uint4* __restrict__ cb,
    const float* __restrict__ c2, float* __restrict__ ynew_out) {
  __shared__ uint4 As[1024];   // 16 KB: 128 rows x 8 slots
  __shared__ uint4 Bs[1024];
  __shared__ float c2s[1024];  // 4 KB

  const int t = threadIdx.x;
  const int w = t >> 6, l = t & 63;
  const int wm = w >> 1, wn = w & 1;
  const int q4 = l >> 4, m16 = l & 15;
  const int row0 = blockIdx.x * 128;

#pragma unroll
  for (int i = 0; i < 4; i++) c2s[t + 256 * i] = c2[t + 256 * i];

  // staging lane mapping: chunk c covers rows c*8..c*8+7 of the tile.
  // lane l -> row_in_chunk = l>>3, slot = l&7, source oct = (l&7) ^ (l>>3).
  const int r_l = l >> 3;
  const int o_l = (l & 7) ^ r_l;
  int aidx[4], bidx[4];
#pragma unroll
  for (int q = 0; q < 4; q++) {
    const int c = w * 4 + q;
    aidx[q] = (row0 + c * 8 + r_l) * 64 + o_l;
    bidx[q] = (c * 8 + r_l) * 64 + o_l;
  }

  // fragment slots: row r, desired oct o -> uint4 idx r*8 + (o ^ (r&7))
  const int xr = m16 & 7;

  float best[16];
  int bi_[16];
#pragma unroll
  for (int i = 0; i < 16; i++) { best[i] = 3.4e38f; bi_[i] = 0; }

  for (int n0 = 0; n0 < KC; n0 += 128) {
    f32x4 acc[4][4];
#pragma unroll
    for (int i = 0; i < 4; i++)
#pragma unroll
      for (int j = 0; j < 4; j++) acc[i][j] = (f32x4){0.f, 0.f, 0.f, 0.f};

    const uint4* bbase = cb + n0 * 64;

    for (int ks = 0; ks < 8; ks++) {
      __syncthreads();  // previous iteration's fragment reads complete
#pragma unroll
      for (int q = 0; q < 4; q++) {
        gld_lds16(xb + aidx[q] + ks * 8, &As[(w * 4 + q) * 64]);
        gld_lds16(bbase + bidx[q] + ks * 8, &Bs[(w * 4 + q) * 64]);
      }
      __syncthreads();  // staging complete (compiler inserts vmcnt drain)
#pragma unroll
      for (int kk = 0; kk < 2; kk++) {
        bf16x8 af[4], bf[4];
        const int oct = kk * 4 + q4;
#pragma unroll
        for (int i = 0; i < 4; i++) {
          const int ra = wm * 64 + i * 16 + m16;
          af[i] = *(const bf16x8*)&As[ra * 8 + (oct ^ xr)];
          const int rb = wn * 64 + i * 16 + m16;
          bf[i] = *(const bf16x8*)&Bs[rb * 8 + (oct ^ xr)];
        }
#pragma unroll
        for (int i = 0; i < 4; i++)
#pragma unroll
          for (int j = 0; j < 4; j++)
            acc[i][j] = __builtin_amdgcn_mfma_f32_16x16x32_bf16(af[i], bf[j], acc[i][j], 0, 0, 0);
      }
    }

    // fold tile into running argmin.  C/D: col=lane&15, row=(lane>>4)*4+reg
#pragma unroll
    for (int j = 0; j < 4; j++) {
      const int n = n0 + wn * 64 + j * 16 + m16;
      const float cc = c2s[n];
#pragma unroll
      for (int i = 0; i < 4; i++)
#pragma unroll
        for (int r = 0; r < 4; r++) {
          float v = fmaf(-2.f, acc[i][j][r], cc);
          const int bi = i * 4 + r;
          if (v < best[bi]) { best[bi] = v; bi_[bi] = n; }
        }
    }
  }

#pragma unroll
  for (int bi = 0; bi < 16; bi++) {
    float v = best[bi];
    int idx = bi_[bi];
#pragma unroll
    for (int off = 8; off; off >>= 1) {
      float ov = __shfl_xor(v, off, 64);
      int oi = __shfl_xor(idx, off, 64);
      if (ov < v || (ov == v && oi < idx)) { v = ov; idx = oi; }
    }
    if (m16 == 0) {
      const int m = wm * 64 + (bi >> 2) * 16 + q4 * 4 + (bi & 3);
      ynew_out[row0 + m] = (float)idx;
    }
  }
}

__global__ __launch_bounds__(256) void loss_final(const float* __restrict__ partial,
                                                  float* __restrict__ out) {
  float s = 0.f;
#pragma unroll
  for (int j = 0; j < 4; j++) s += partial[threadIdx.x + 256 * j];
#pragma unroll
  for (int off = 32; off; off >>= 1) s += __shfl_down(s, off, 64);
  __shared__ float ps[4];
  if ((threadIdx.x & 63) == 0) ps[threadIdx.x >> 6] = s;
  __syncthreads();
  if (threadIdx.x == 0) out[0] = ps[0] + ps[1] + ps[2] + ps[3];
}

// ================= FALLBACK PATH (R2, used only if ws too small) =================

#define SLOT(row, oct) (16 * (oct) + (((row) & 15) ^ (((oct) & 2) << 1)))

__device__ __forceinline__ void split_pack(const float4& a, const float4& b,
                                           uint4& hi, uint4& lo) {
  float f[8] = {a.x, a.y, a.z, a.w, b.x, b.y, b.z, b.w};
  uint hw[4], lw[4];
#pragma unroll
  for (int i = 0; i < 4; i++) {
    uint e0 = __float_as_uint(f[2 * i]), e1 = __float_as_uint(f[2 * i + 1]);
    hw[i] = (e0 >> 16) | (e1 & 0xffff0000u);
    float l0 = f[2 * i]     - __uint_as_float(e0 & 0xffff0000u);
    float l1 = f[2 * i + 1] - __uint_as_float(e1 & 0xffff0000u);
    lw[i] = (__float_as_uint(l0) >> 16) | (__float_as_uint(l1) & 0xffff0000u);
  }
  hi = make_uint4(hw[0], hw[1], hw[2], hw[3]);
  lo = make_uint4(lw[0], lw[1], lw[2], lw[3]);
}

__global__ __launch_bounds__(256) void c2_kernel(const float* __restrict__ centers,
                                                 float* __restrict__ c2) {
  int wave = (blockIdx.x * 256 + threadIdx.x) >> 6;
  int lane = threadIdx.x & 63;
  const float4* c4 = (const float4*)(centers + (size_t)wave * DD);
  float s = 0.f;
#pragma unroll
  for (int j = 0; j < 2; j++) {
    float4 v = c4[lane + 64 * j];
    s += v.x * v.x + v.y * v.y + v.z * v.z + v.w * v.w;
  }
#pragma unroll
  for (int off = 32; off; off >>= 1) s += __shfl_down(s, off, 64);
  if (lane == 0) c2[wave] = s;
}

__global__ __launch_bounds__(256, 2) void argmin_fb(
    const float* __restrict__ x, const float* __restrict__ centers,
    const float* __restrict__ c2, float* __restrict__ ynew_out) {
  __shared__ uint4 Ah[512], Al[512], Bh[512], Bl[512];
  const int t = threadIdx.x;
  const int w = t >> 6, l = t & 63;
  const int wm = w >> 1, wn = w & 1;
  const size_t row0 = (size_t)blockIdx.x * 128;
  const int srow = t >> 1, h = t & 1;
  const int mt = srow >> 4;
  const int so0 = mt * 64 + SLOT(srow, 2 * h);
  const int so1 = mt * 64 + SLOT(srow, 2 * h + 1);
  const int rs = SLOT(l & 15, l >> 4);
  const float* xp = x + (row0 + srow) * DD + h * 16;
  float best[16];
  int bidx[16];
#pragma unroll
  for (int i = 0; i < 16; i++) { best[i] = 3.4e38f; bidx[i] = 0; }
  for (int n0 = 0; n0 < KC; n0 += 128) {
    const float* bp = centers + (size_t)(n0 + srow) * DD + h * 16;
    f32x4 acc[4][4];
#pragma unroll
    for (int i = 0; i < 4; i++)
#pragma unroll
      for (int j = 0; j < 4; j++) acc[i][j] = (f32x4){0.f, 0.f, 0.f, 0.f};
    float4 ra[4], rb[4];
#pragma unroll
    for (int q = 0; q < 4; q++) {
      ra[q] = *(const float4*)(xp + q * 4);
      rb[q] = *(const float4*)(bp + q * 4);
    }
    for (int ks = 0; ks < 16; ks++) {
      uint4 ah0, al0, ah1, al1, bh0, bl0, bh1, bl1;
      split_pack(ra[0], ra[1], ah0, al0);
      split_pack(ra[2], ra[3], ah1, al1);
      split_pack(rb[0], rb[1], bh0, bl0);
      split_pack(rb[2], rb[3], bh1, bl1);
      __syncthreads();
      Ah[so0] = ah0; Al[so0] = al0;
      Ah[so1] = ah1; Al[so1] = al1;
      Bh[so0] = bh0; Bl[so0] = bl0;
      Bh[so1] = bh1; Bl[so1] = bl1;
      __syncthreads();
      if (ks < 15) {
#pragma unroll
        for (int q = 0; q < 4; q++) {
          ra[q] = *(const float4*)(xp + (ks + 1) * 32 + q * 4);
          rb[q] = *(const float4*)(bp + (ks + 1) * 32 + q * 4);
        }
      }
      bf16x8 afh[4], afl[4], bfh[4], bfl[4];
#pragma unroll
      for (int i = 0; i < 4; i++) {
        afh[i] = *(const bf16x8*)&Ah[(wm * 4 + i) * 64 + rs];
        afl[i] = *(const bf16x8*)&Al[(wm * 4 + i) * 64 + rs];
        bfh[i] = *(const bf16x8*)&Bh[(wn * 4 + i) * 64 + rs];
        bfl[i] = *(const bf16x8*)&Bl[(wn * 4 + i) * 64 + rs];
      }
#pragma unroll
      for (int i = 0; i < 4; i++)
#pragma unroll
        for (int j = 0; j < 4; j++) {
          acc[i][j] = __builtin_amdgcn_mfma_f32_16x16x32_bf16(afh[i], bfh[j], acc[i][j], 0, 0, 0);
          acc[i][j] = __builtin_amdgcn_mfma_f32_16x16x32_bf16(afl[i], bfh[j], acc[i][j], 0, 0, 0);
          acc[i][j] = __builtin_amdgcn_mfma_f32_16x16x32_bf16(afh[i], bfl[j], acc[i][j], 0, 0, 0);
        }
    }
#pragma unroll
    for (int j = 0; j < 4; j++) {
      int n = n0 + wn * 64 + j * 16 + (l & 15);
      float cc = c2[n];
#pragma unroll
      for (int i = 0; i < 4; i++)
#pragma unroll
        for (int r = 0; r < 4; r++) {
          float v = fmaf(-2.f, acc[i][j][r], cc);
          int bi = i * 4 + r;
          if (v < best[bi]) { best[bi] = v; bidx[bi] = n; }
        }
    }
  }
#pragma unroll
  for (int bi = 0; bi < 16; bi++) {
    float v = best[bi];
    int idx = bidx[bi];
#pragma unroll
    for (int off = 8; off; off >>= 1) {
      float ov = __shfl_xor(v, off, 64);
      int oi = __shfl_xor(idx, off, 64);
      if (ov < v || (ov == v && oi < idx)) { v = ov; idx = oi; }
    }
    if ((l & 15) == 0) {
      int m = wm * 64 + (bi >> 2) * 16 + (l >> 4) * 4 + (bi & 3);
      ynew_out[row0 + m] = (float)idx;
    }
  }
}

__global__ __launch_bounds__(256) void loss_partial_fb(
    const float* __restrict__ x, const int* __restrict__ y,
    const float* __restrict__ centers, float* __restrict__ partial) {
  const int w = threadIdx.x >> 6, l = threadIdx.x & 63;
  const int base = blockIdx.x * 64 + w * 16;
  float s = 0.f;
  for (int p = 0; p < 16; p++) {
    int i = base + p;
    const float4* x4 = (const float4*)(x + (size_t)i * DD);
    const float4* c4 = (const float4*)(centers + (size_t)y[i] * DD);
#pragma unroll
    for (int j = 0; j < 2; j++) {
      float4 xv = x4[l + 64 * j], cv = c4[l + 64 * j];
      float dx = xv.x - cv.x, dy = xv.y - cv.y, dz = xv.z - cv.z, dw = xv.w - cv.w;
      s += dx * dx + dy * dy + dz * dz + dw * dw;
    }
  }
#pragma unroll
  for (int off = 32; off; off >>= 1) s += __shfl_down(s, off, 64);
  __shared__ float ps[4];
  if (l == 0) ps[w] = s;
  __syncthreads();
  if (threadIdx.x == 0) partial[blockIdx.x] = ps[0] + ps[1] + ps[2] + ps[3];
}

// ================= launcher =================

extern "C" void kernel_launch(void* const* d_in, const int* in_sizes, int n_in,
                              void* d_out, int out_size, void* d_ws, size_t ws_size,
                              hipStream_t stream) {
  const float* x       = (const float*)d_in[0];
  const int*   y       = (const int*)d_in[1];
  const float* centers = (const float*)d_in[2];
  float* out = (float*)d_out;  // out[0] = loss, out[1..] = ynew as float

  const size_t xb_bytes = (size_t)NPTS * DD * 2;  // 64 MB
  const size_t cb_bytes = (size_t)KC * DD * 2;    // 1 MB
  const size_t need = xb_bytes + cb_bytes + (KC + 1024) * sizeof(float);

  if (ws_size >= need) {
    uint4* xb      = (uint4*)d_ws;
    uint4* cbp     = (uint4*)((char*)d_ws + xb_bytes);
    float* c2      = (float*)((char*)d_ws + xb_bytes + cb_bytes);
    float* partial = c2 + KC;
    convert_c<<<KC / 4, 256, 0, stream>>>(centers, cbp, c2);
    convert_x_loss<<<NPTS / 64, 256, 0, stream>>>(x, y, centers, xb, partial);
    gemm_argmin<<<NPTS / 128, 256, 0, stream>>>(xb, cbp, c2, out + 1);
    loss_final<<<1, 256, 0, stream>>>(partial, out);
  } else {
    float* c2      = (float*)d_ws;
    float* partial = c2 + KC;
    c2_kernel<<<KC / 4, 256, 0, stream>>>(centers, c2);
    argmin_fb<<<NPTS / 128, 256, 0, stream>>>(x, centers, c2, out + 1);
    loss_partial_fb<<<NPTS / 64, 256, 0, stream>>>(x, y, centers, partial);
    loss_final<<<1, 256, 0, stream>>>(partial, out);
  }
}

// Round 4
// 273.977 us; speedup vs baseline: 4.6220x; 1.0555x over previous
//
#include <hip/hip_runtime.h>

#define NPTS 65536
#define KC   1024
#define DD   512

using bf16x8 = __attribute__((ext_vector_type(8))) __bf16;
using f32x4  = __attribute__((ext_vector_type(4))) float;

// ---- async global->LDS, 16B per lane. LDS dest = wave-uniform base + lane*16.
__device__ __forceinline__ void gld_lds16(const void* g, void* lds_base) {
  __builtin_amdgcn_global_load_lds(
      (const __attribute__((address_space(1))) unsigned int*)(uintptr_t)g,
      (__attribute__((address_space(3))) unsigned int*)(unsigned int)(uintptr_t)lds_base,
      16, 0, 0);
}

// pack float4 -> 4 bf16 (truncation)
__device__ __forceinline__ uint2 pack4(const float4& v) {
  uint2 r;
  r.x = (__float_as_uint(v.x) >> 16) | (__float_as_uint(v.y) & 0xffff0000u);
  r.y = (__float_as_uint(v.z) >> 16) | (__float_as_uint(v.w) & 0xffff0000u);
  return r;
}

// ================= FAST PATH =================

// one WAVE per row: convert x->bf16 and accumulate exact-fp32 loss term.
// No long serial dependence chains; 16384 blocks saturate latency hiding.
__global__ __launch_bounds__(256) void convert_x_loss(
    const float* __restrict__ x, const int* __restrict__ y,
    const float* __restrict__ centers, uint4* __restrict__ xb,
    float* __restrict__ partial) {
  const int w = threadIdx.x >> 6, l = threadIdx.x & 63;
  const int row = blockIdx.x * 4 + w;
  const float4* xr = (const float4*)(x + (size_t)row * DD);
  float4 a = xr[2 * l];
  float4 b = xr[2 * l + 1];
  uint2 pa = pack4(a), pb = pack4(b);
  xb[row * 64 + l] = make_uint4(pa.x, pa.y, pb.x, pb.y);
  const int yr = y[row];
  const float4* cr = (const float4*)(centers + (size_t)yr * DD);
  float4 ca = cr[2 * l];
  float4 cb = cr[2 * l + 1];
  float d0 = a.x - ca.x, d1 = a.y - ca.y, d2 = a.z - ca.z, d3 = a.w - ca.w;
  float d4 = b.x - cb.x, d5 = b.y - cb.y, d6 = b.z - cb.z, d7 = b.w - cb.w;
  float s = d0 * d0 + d1 * d1 + d2 * d2 + d3 * d3 +
            d4 * d4 + d5 * d5 + d6 * d6 + d7 * d7;
#pragma unroll
  for (int off = 32; off; off >>= 1) s += __shfl_down(s, off, 64);
  __shared__ float ps[4];
  if (l == 0) ps[w] = s;
  __syncthreads();
  if (threadIdx.x == 0) partial[blockIdx.x] = ps[0] + ps[1] + ps[2] + ps[3];
}

// centers -> bf16 + c2.  one wave per center row.
__global__ __launch_bounds__(256) void convert_c(
    const float* __restrict__ centers, uint4* __restrict__ cb,
    float* __restrict__ c2) {
  const int row = (blockIdx.x * 256 + threadIdx.x) >> 6;
  const int l = threadIdx.x & 63;
  const float4* cf4 = (const float4*)centers;
  float4 a = cf4[row * 128 + 2 * l];
  float4 b = cf4[row * 128 + 2 * l + 1];
  uint2 pa = pack4(a), pb = pack4(b);
  cb[row * 64 + l] = make_uint4(pa.x, pa.y, pb.x, pb.y);
  float s = a.x * a.x + a.y * a.y + a.z * a.z + a.w * a.w +
            b.x * b.x + b.y * b.y + b.z * b.z + b.w * b.w;
#pragma unroll
  for (int off = 32; off; off >>= 1) s += __shfl_down(s, off, 64);
  if (l == 0) c2[row] = s;
}

// bf16 MFMA argmin, BM=128 x BN=256, BK=64.  64 MFMA per barrier window,
// A re-fetched only 4x.  LDS: As 16KB + Bs 32KB + c2s 4KB = 52KB (2 blocks/CU).
__global__ __launch_bounds__(256, 2) void gemm_argmin(
    const uint4* __restrict__ xb, const uint4* __restrict__ cb,
    const float* __restrict__ c2, float* __restrict__ ynew_out) {
  __shared__ uint4 As[1024];   // 128 rows x 8 slots (64 bf16/row chunk)
  __shared__ uint4 Bs[2048];   // 256 rows x 8 slots
  __shared__ float c2s[1024];

  const int t = threadIdx.x;
  const int w = t >> 6, l = t & 63;
  const int wm = w >> 1, wn = w & 1;   // wave: 64 rows x 128 cols
  const int q4 = l >> 4, m16 = l & 15;
  const int row0 = blockIdx.x * 128;

#pragma unroll
  for (int i = 0; i < 4; i++) c2s[t + 256 * i] = c2[t + 256 * i];

  // staging lane mapping: chunk covers 8 rows; lane l -> row l>>3, slot l&7,
  // source oct (l&7)^(l>>3)  => LDS slot(r,oct) = oct ^ (r&7)  (conflict-free)
  const int r_l = l >> 3;
  const int o_l = (l & 7) ^ r_l;
  int aidx[4];     // A: 16 chunks, wave stages 4
#pragma unroll
  for (int q = 0; q < 4; q++)
    aidx[q] = (row0 + (w * 4 + q) * 8 + r_l) * 64 + o_l;
  int bsrc[8];     // B: 32 chunks, wave stages 8 (relative to n0 base)
#pragma unroll
  for (int q = 0; q < 8; q++)
    bsrc[q] = ((w * 8 + q) * 8 + r_l) * 64 + o_l;

  const int xr = m16 & 7;

  float best[16];
  int bi_[16];
#pragma unroll
  for (int i = 0; i < 16; i++) { best[i] = 3.4e38f; bi_[i] = 0; }

  for (int n0 = 0; n0 < KC; n0 += 256) {
    f32x4 acc[4][8];
#pragma unroll
    for (int i = 0; i < 4; i++)
#pragma unroll
      for (int j = 0; j < 8; j++) acc[i][j] = (f32x4){0.f, 0.f, 0.f, 0.f};

    const uint4* bbase = cb + n0 * 64;

    for (int ks = 0; ks < 8; ks++) {
      __syncthreads();  // previous iteration's fragment reads complete
#pragma unroll
      for (int q = 0; q < 4; q++)
        gld_lds16(xb + aidx[q] + ks * 8, &As[(w * 4 + q) * 64]);
#pragma unroll
      for (int q = 0; q < 8; q++)
        gld_lds16(bbase + bsrc[q] + ks * 8, &Bs[(w * 8 + q) * 64]);
      __syncthreads();  // staging complete
#pragma unroll
      for (int kk = 0; kk < 2; kk++) {
        const int oct = kk * 4 + q4;
        bf16x8 af[4];
#pragma unroll
        for (int i = 0; i < 4; i++) {
          const int ra = wm * 64 + i * 16 + m16;
          af[i] = *(const bf16x8*)&As[ra * 8 + (oct ^ xr)];
        }
#pragma unroll
        for (int j = 0; j < 8; j++) {
          const int rb = wn * 128 + j * 16 + m16;
          bf16x8 bf = *(const bf16x8*)&Bs[rb * 8 + (oct ^ xr)];
#pragma unroll
          for (int i = 0; i < 4; i++)
            acc[i][j] = __builtin_amdgcn_mfma_f32_16x16x32_bf16(af[i], bf, acc[i][j], 0, 0, 0);
        }
      }
    }

    // fold tile into running argmin.  C/D: col=lane&15, row=(lane>>4)*4+reg
#pragma unroll
    for (int j = 0; j < 8; j++) {
      const int n = n0 + wn * 128 + j * 16 + m16;
      const float cc = c2s[n];
#pragma unroll
      for (int i = 0; i < 4; i++)
#pragma unroll
        for (int r = 0; r < 4; r++) {
          float v = fmaf(-2.f, acc[i][j][r], cc);
          const int bi = i * 4 + r;
          if (v < best[bi]) { best[bi] = v; bi_[bi] = n; }
        }
    }
  }

#pragma unroll
  for (int bi = 0; bi < 16; bi++) {
    float v = best[bi];
    int idx = bi_[bi];
#pragma unroll
    for (int off = 8; off; off >>= 1) {
      float ov = __shfl_xor(v, off, 64);
      int oi = __shfl_xor(idx, off, 64);
      if (ov < v || (ov == v && oi < idx)) { v = ov; idx = oi; }
    }
    if (m16 == 0) {
      const int m = wm * 64 + (bi >> 2) * 16 + q4 * 4 + (bi & 3);
      ynew_out[row0 + m] = (float)idx;
    }
  }
}

__global__ __launch_bounds__(256) void loss_final(const float* __restrict__ partial,
                                                  float* __restrict__ out) {
  float s = 0.f;
#pragma unroll
  for (int j = 0; j < 64; j++) s += partial[threadIdx.x + 256 * j];
#pragma unroll
  for (int off = 32; off; off >>= 1) s += __shfl_down(s, off, 64);
  __shared__ float ps[4];
  if ((threadIdx.x & 63) == 0) ps[threadIdx.x >> 6] = s;
  __syncthreads();
  if (threadIdx.x == 0) out[0] = ps[0] + ps[1] + ps[2] + ps[3];
}

// ================= FALLBACK PATH (R2, used only if ws too small) =================

#define SLOT(row, oct) (16 * (oct) + (((row) & 15) ^ (((oct) & 2) << 1)))

__device__ __forceinline__ void split_pack(const float4& a, const float4& b,
                                           uint4& hi, uint4& lo) {
  float f[8] = {a.x, a.y, a.z, a.w, b.x, b.y, b.z, b.w};
  uint hw[4], lw[4];
#pragma unroll
  for (int i = 0; i < 4; i++) {
    uint e0 = __float_as_uint(f[2 * i]), e1 = __float_as_uint(f[2 * i + 1]);
    hw[i] = (e0 >> 16) | (e1 & 0xffff0000u);
    float l0 = f[2 * i]     - __uint_as_float(e0 & 0xffff0000u);
    float l1 = f[2 * i + 1] - __uint_as_float(e1 & 0xffff0000u);
    lw[i] = (__float_as_uint(l0) >> 16) | (__float_as_uint(l1) & 0xffff0000u);
  }
  hi = make_uint4(hw[0], hw[1], hw[2], hw[3]);
  lo = make_uint4(lw[0], lw[1], lw[2], lw[3]);
}

__global__ __launch_bounds__(256) void c2_kernel(const float* __restrict__ centers,
                                                 float* __restrict__ c2) {
  int wave = (blockIdx.x * 256 + threadIdx.x) >> 6;
  int lane = threadIdx.x & 63;
  const float4* c4 = (const float4*)(centers + (size_t)wave * DD);
  float s = 0.f;
#pragma unroll
  for (int j = 0; j < 2; j++) {
    float4 v = c4[lane + 64 * j];
    s += v.x * v.x + v.y * v.y + v.z * v.z + v.w * v.w;
  }
#pragma unroll
  for (int off = 32; off; off >>= 1) s += __shfl_down(s, off, 64);
  if (lane == 0) c2[wave] = s;
}

__global__ __launch_bounds__(256, 2) void argmin_fb(
    const float* __restrict__ x, const float* __restrict__ centers,
    const float* __restrict__ c2, float* __restrict__ ynew_out) {
  __shared__ uint4 Ah[512], Al[512], Bh[512], Bl[512];
  const int t = threadIdx.x;
  const int w = t >> 6, l = t & 63;
  const int wm = w >> 1, wn = w & 1;
  const size_t row0 = (size_t)blockIdx.x * 128;
  const int srow = t >> 1, h = t & 1;
  const int mt = srow >> 4;
  const int so0 = mt * 64 + SLOT(srow, 2 * h);
  const int so1 = mt * 64 + SLOT(srow, 2 * h + 1);
  const int rs = SLOT(l & 15, l >> 4);
  const float* xp = x + (row0 + srow) * DD + h * 16;
  float best[16];
  int bidx[16];
#pragma unroll
  for (int i = 0; i < 16; i++) { best[i] = 3.4e38f; bidx[i] = 0; }
  for (int n0 = 0; n0 < KC; n0 += 128) {
    const float* bp = centers + (size_t)(n0 + srow) * DD + h * 16;
    f32x4 acc[4][4];
#pragma unroll
    for (int i = 0; i < 4; i++)
#pragma unroll
      for (int j = 0; j < 4; j++) acc[i][j] = (f32x4){0.f, 0.f, 0.f, 0.f};
    float4 ra[4], rb[4];
#pragma unroll
    for (int q = 0; q < 4; q++) {
      ra[q] = *(const float4*)(xp + q * 4);
      rb[q] = *(const float4*)(bp + q * 4);
    }
    for (int ks = 0; ks < 16; ks++) {
      uint4 ah0, al0, ah1, al1, bh0, bl0, bh1, bl1;
      split_pack(ra[0], ra[1], ah0, al0);
      split_pack(ra[2], ra[3], ah1, al1);
      split_pack(rb[0], rb[1], bh0, bl0);
      split_pack(rb[2], rb[3], bh1, bl1);
      __syncthreads();
      Ah[so0] = ah0; Al[so0] = al0;
      Ah[so1] = ah1; Al[so1] = al1;
      Bh[so0] = bh0; Bl[so0] = bl0;
      Bh[so1] = bh1; Bl[so1] = bl1;
      __syncthreads();
      if (ks < 15) {
#pragma unroll
        for (int q = 0; q < 4; q++) {
          ra[q] = *(const float4*)(xp + (ks + 1) * 32 + q * 4);
          rb[q] = *(const float4*)(bp + (ks + 1) * 32 + q * 4);
        }
      }
      bf16x8 afh[4], afl[4], bfh[4], bfl[4];
#pragma unroll
      for (int i = 0; i < 4; i++) {
        afh[i] = *(const bf16x8*)&Ah[(wm * 4 + i) * 64 + rs];
        afl[i] = *(const bf16x8*)&Al[(wm * 4 + i) * 64 + rs];
        bfh[i] = *(const bf16x8*)&Bh[(wn * 4 + i) * 64 + rs];
        bfl[i] = *(const bf16x8*)&Bl[(wn * 4 + i) * 64 + rs];
      }
#pragma unroll
      for (int i = 0; i < 4; i++)
#pragma unroll
        for (int j = 0; j < 4; j++) {
          acc[i][j] = __builtin_amdgcn_mfma_f32_16x16x32_bf16(afh[i], bfh[j], acc[i][j], 0, 0, 0);
          acc[i][j] = __builtin_amdgcn_mfma_f32_16x16x32_bf16(afl[i], bfh[j], acc[i][j], 0, 0, 0);
          acc[i][j] = __builtin_amdgcn_mfma_f32_16x16x32_bf16(afh[i], bfl[j], acc[i][j], 0, 0, 0);
        }
    }
#pragma unroll
    for (int j = 0; j < 4; j++) {
      int n = n0 + wn * 64 + j * 16 + (l & 15);
      float cc = c2[n];
#pragma unroll
      for (int i = 0; i < 4; i++)
#pragma unroll
        for (int r = 0; r < 4; r++) {
          float v = fmaf(-2.f, acc[i][j][r], cc);
          int bi = i * 4 + r;
          if (v < best[bi]) { best[bi] = v; bidx[bi] = n; }
        }
    }
  }
#pragma unroll
  for (int bi = 0; bi < 16; bi++) {
    float v = best[bi];
    int idx = bidx[bi];
#pragma unroll
    for (int off = 8; off; off >>= 1) {
      float ov = __shfl_xor(v, off, 64);
      int oi = __shfl_xor(idx, off, 64);
      if (ov < v || (ov == v && oi < idx)) { v = ov; idx = oi; }
    }
    if ((l & 15) == 0) {
      int m = wm * 64 + (bi >> 2) * 16 + (l >> 4) * 4 + (bi & 3);
      ynew_out[row0 + m] = (float)idx;
    }
  }
}

__global__ __launch_bounds__(256) void loss_partial_fb(
    const float* __restrict__ x, const int* __restrict__ y,
    const float* __restrict__ centers, float* __restrict__ partial) {
  const int w = threadIdx.x >> 6, l = threadIdx.x & 63;
  const int row = blockIdx.x * 4 + w;
  const float4* x4 = (const float4*)(x + (size_t)row * DD);
  const float4* c4 = (const float4*)(centers + (size_t)y[row] * DD);
  float s = 0.f;
#pragma unroll
  for (int j = 0; j < 2; j++) {
    float4 xv = x4[2 * l + j], cv = c4[2 * l + j];
    float dx = xv.x - cv.x, dy = xv.y - cv.y, dz = xv.z - cv.z, dw = xv.w - cv.w;
    s += dx * dx + dy * dy + dz * dz + dw * dw;
  }
#pragma unroll
  for (int off = 32; off; off >>= 1) s += __shfl_down(s, off, 64);
  __shared__ float ps[4];
  if (l == 0) ps[w] = s;
  __syncthreads();
  if (threadIdx.x == 0) partial[blockIdx.x] = ps[0] + ps[1] + ps[2] + ps[3];
}

// ================= launcher =================

extern "C" void kernel_launch(void* const* d_in, const int* in_sizes, int n_in,
                              void* d_out, int out_size, void* d_ws, size_t ws_size,
                              hipStream_t stream) {
  const float* x       = (const float*)d_in[0];
  const int*   y       = (const int*)d_in[1];
  const float* centers = (const float*)d_in[2];
  float* out = (float*)d_out;  // out[0] = loss, out[1..] = ynew as float

  const size_t xb_bytes = (size_t)NPTS * DD * 2;  // 64 MB
  const size_t cb_bytes = (size_t)KC * DD * 2;    // 1 MB
  const size_t need = xb_bytes + cb_bytes + (KC + NPTS / 4) * sizeof(float);

  if (ws_size >= need) {
    uint4* xb      = (uint4*)d_ws;
    uint4* cbp     = (uint4*)((char*)d_ws + xb_bytes);
    float* c2      = (float*)((char*)d_ws + xb_bytes + cb_bytes);
    float* partial = c2 + KC;
    convert_c<<<KC / 4, 256, 0, stream>>>(centers, cbp, c2);
    convert_x_loss<<<NPTS / 4, 256, 0, stream>>>(x, y, centers, xb, partial);
    gemm_argmin<<<NPTS / 128, 256, 0, stream>>>(xb, cbp, c2, out + 1);
    loss_final<<<1, 256, 0, stream>>>(partial, out);
  } else {
    float* c2      = (float*)d_ws;
    float* partial = c2 + KC;
    c2_kernel<<<KC / 4, 256, 0, stream>>>(centers, c2);
    argmin_fb<<<NPTS / 128, 256, 0, stream>>>(x, centers, c2, out + 1);
    loss_partial_fb<<<NPTS / 4, 256, 0, stream>>>(x, y, centers, partial);
    loss_final<<<1, 256, 0, stream>>>(partial, out);
  }
}